// Round 2
// baseline (578.041 us; speedup 1.0000x reference)
//
#include <hip/hip_runtime.h>

#define BATCH 64
#define LXN 512
#define LYN 512
#define DIMN 64
#define BIGF 1e30f

// ---------------------------------------------------------------------------
// Kernel 1: D[b][i][j] = ||X[b,i] - Y[b,j]||^2  = x2 + y2 - 2*x.y
// 64x64 output tile per block, 256 threads, 4x4 micro-tile per thread.
// LDS holds X-tile and Y-tile transposed to [k][i] so fragment reads are
// contiguous ds_read_b128. Row stride 68 floats keeps 16B alignment.
// blockIdx.z = batch index WITHIN the current chunk (X/Y/D pre-offset).
// ---------------------------------------------------------------------------
__global__ __launch_bounds__(256) void dist_kernel(const float* __restrict__ X,
                                                   const float* __restrict__ Y,
                                                   float* __restrict__ D) {
    __shared__ float Xs[DIMN][68];
    __shared__ float Ys[DIMN][68];
    __shared__ float x2s[64];
    __shared__ float y2s[64];

    const int b  = blockIdx.z;
    const int i0 = blockIdx.y * 64;
    const int j0 = blockIdx.x * 64;
    const int t  = threadIdx.x;

    const float4* xsrc = (const float4*)(X + ((size_t)b * LXN + i0) * DIMN);
    const float4* ysrc = (const float4*)(Y + ((size_t)b * LYN + j0) * DIMN);
#pragma unroll
    for (int s = 0; s < 4; ++s) {
        int idx = s * 256 + t;          // float4 index within the tile
        int r   = idx >> 4;             // tile row (16 float4 per row)
        int d0  = (idx & 15) * 4;       // starting k
        float4 v = xsrc[idx];
        Xs[d0 + 0][r] = v.x; Xs[d0 + 1][r] = v.y;
        Xs[d0 + 2][r] = v.z; Xs[d0 + 3][r] = v.w;
        float4 w = ysrc[idx];
        Ys[d0 + 0][r] = w.x; Ys[d0 + 1][r] = w.y;
        Ys[d0 + 2][r] = w.z; Ys[d0 + 3][r] = w.w;
    }
    __syncthreads();

    if (t < 64) {
        float s = 0.f;
#pragma unroll
        for (int k = 0; k < DIMN; ++k) { float v = Xs[k][t]; s += v * v; }
        x2s[t] = s;
    } else if (t < 128) {
        int c = t - 64;
        float s = 0.f;
#pragma unroll
        for (int k = 0; k < DIMN; ++k) { float v = Ys[k][c]; s += v * v; }
        y2s[c] = s;
    }
    __syncthreads();

    const int tx = t & 15;   // j micro-tile
    const int ty = t >> 4;   // i micro-tile
    float acc[4][4];
#pragma unroll
    for (int r = 0; r < 4; ++r)
#pragma unroll
        for (int c = 0; c < 4; ++c) acc[r][c] = 0.f;

#pragma unroll 4
    for (int k = 0; k < DIMN; ++k) {
        float4 a  = *(const float4*)&Xs[k][ty * 4];
        float4 bv = *(const float4*)&Ys[k][tx * 4];
        float ar[4] = {a.x, a.y, a.z, a.w};
        float bc[4] = {bv.x, bv.y, bv.z, bv.w};
#pragma unroll
        for (int r = 0; r < 4; ++r)
#pragma unroll
            for (int c = 0; c < 4; ++c) acc[r][c] += ar[r] * bc[c];
    }

    float* outp = D + (((size_t)b * LXN + (i0 + ty * 4)) * LYN + j0 + tx * 4);
    float yy0 = y2s[tx * 4 + 0], yy1 = y2s[tx * 4 + 1];
    float yy2 = y2s[tx * 4 + 2], yy3 = y2s[tx * 4 + 3];
#pragma unroll
    for (int r = 0; r < 4; ++r) {
        float xx = x2s[ty * 4 + r];
        float4 o;
        o.x = xx + yy0 - 2.f * acc[r][0];
        o.y = xx + yy1 - 2.f * acc[r][1];
        o.z = xx + yy2 - 2.f * acc[r][2];
        o.w = xx + yy3 - 2.f * acc[r][3];
        *(float4*)(outp + (size_t)r * LYN) = o;
    }
}

// ---------------------------------------------------------------------------
// Kernel 2: soft-DTW over anti-diagonals. One block per batch (within chunk),
// thread i owns row i. Per diagonal t, cell (i, j=t-i):
//   v_left = R[i][j-1]   -> own previous value (register)
//   v_up   = R[i-1][j]   -> neighbor's previous value (one LDS read)
//   v_diag = R[i-1][j-1] -> neighbor value read LAST iteration (register)
// Parity double-buffer + single __syncthreads per diagonal (read parity and
// write parity are disjoint within one barrier interval).
// ---------------------------------------------------------------------------
__global__ __launch_bounds__(512) void sdtw_kernel(const float* __restrict__ D,
                                                   float* __restrict__ out) {
    __shared__ float rbuf[2][LXN + 1];
    const int i = threadIdx.x;
    const int b = blockIdx.x;
    const float* row = D + ((size_t)b * LXN + i) * LYN;

    rbuf[0][i] = BIGF;
    rbuf[1][i] = BIGF;
    __syncthreads();

    float r_prev  = BIGF;  // R[i][j-1]   (own value at t-1)
    float nb_prev = BIGF;  // R[i-1][j-1] (neighbor value at t-2)
    float4 dbuf   = make_float4(0.f, 0.f, 0.f, 0.f);
    const int im1 = (i == 0) ? 0 : (i - 1);

    for (int t = 0; t < LXN + LYN - 1; ++t) {
        int j = t - i;
        bool valid = (j >= 0) && (j < LYN);

        float up_read = rbuf[(t + 1) & 1][im1];       // written at t-1
        float v_up   = (i == 0) ? BIGF : up_read;
        float v_diag = (i == 0) ? ((t == 0) ? 0.f : BIGF) : nb_prev;
        nb_prev = v_up;
        float v_left = r_prev;

        // softmin_gamma, gamma = 1 (min-shifted logsumexp, same math as ref)
        float m = fminf(v_diag, fminf(v_up, v_left));
        float ssum = __expf(m - v_diag) + __expf(m - v_up) + __expf(m - v_left);
        float smin = m - __logf(ssum);

        // Per-lane rolling float4 D buffer: refill every 4th valid j.
        if (valid && ((j & 3) == 0)) dbuf = *(const float4*)(row + j);
        int ph = j & 3;
        float dval = (ph == 0) ? dbuf.x : (ph == 1) ? dbuf.y
                   : (ph == 2) ? dbuf.z : dbuf.w;

        float r_cur = valid ? (dval + smin) : BIGF;
        rbuf[t & 1][i] = r_cur;
        r_prev = r_cur;
        __syncthreads();
    }

    if (i == LXN - 1) out[b] = r_prev;
}

extern "C" void kernel_launch(void* const* d_in, const int* in_sizes, int n_in,
                              void* d_out, int out_size, void* d_ws, size_t ws_size,
                              hipStream_t stream) {
    const float* X = (const float*)d_in[0];
    const float* Y = (const float*)d_in[1];
    float* Dws = (float*)d_ws;
    float* out = (float*)d_out;

    // Workspace-size-adaptive chunking: never write more than ws_size bytes.
    const size_t per_batch = (size_t)LXN * LYN * sizeof(float);  // 1 MiB
    int chunk = (int)(ws_size / per_batch);
    if (chunk > BATCH) chunk = BATCH;
    if (chunk < 1) chunk = 1;  // ws_size >= 1 MiB assumed

    for (int b0 = 0; b0 < BATCH; b0 += chunk) {
        int nb = BATCH - b0 < chunk ? BATCH - b0 : chunk;
        dist_kernel<<<dim3(LYN / 64, LXN / 64, nb), 256, 0, stream>>>(
            X + (size_t)b0 * LXN * DIMN, Y + (size_t)b0 * LYN * DIMN, Dws);
        sdtw_kernel<<<nb, 512, 0, stream>>>(Dws, out + b0);
    }
}

// Round 3
// 372.425 us; speedup vs baseline: 1.5521x; 1.5521x over previous
//
#include <hip/hip_runtime.h>

#define BATCH 64
#define LXN 512
#define LYN 512
#define DIMN 64
#define BIGF 1e30f
#define INV_LN2 1.4426950408889634f
#define LN2F    0.6931471805599453f

// ---------------------------------------------------------------------------
// Kernel 1: D'[b][i][j] = ||X[b,i] - Y[b,j]||^2 / ln2   (base-2 domain)
// written in TILE layout: offset = b*2^18 + ((i>>3)*64 + (j>>3))*64
//                                  + (i&7)*8 + (j&7)
// so each 8x8 tile is 64 contiguous floats (16 float4s) for sdtw_kernel.
// ---------------------------------------------------------------------------
__global__ __launch_bounds__(256) void dist_kernel(const float* __restrict__ X,
                                                   const float* __restrict__ Y,
                                                   float* __restrict__ D) {
    __shared__ float Xs[DIMN][68];
    __shared__ float Ys[DIMN][68];
    __shared__ float x2s[64];
    __shared__ float y2s[64];

    const int b  = blockIdx.z;
    const int i0 = blockIdx.y * 64;
    const int j0 = blockIdx.x * 64;
    const int t  = threadIdx.x;

    const float4* xsrc = (const float4*)(X + ((size_t)b * LXN + i0) * DIMN);
    const float4* ysrc = (const float4*)(Y + ((size_t)b * LYN + j0) * DIMN);
#pragma unroll
    for (int s = 0; s < 4; ++s) {
        int idx = s * 256 + t;
        int r   = idx >> 4;
        int d0  = (idx & 15) * 4;
        float4 v = xsrc[idx];
        Xs[d0 + 0][r] = v.x; Xs[d0 + 1][r] = v.y;
        Xs[d0 + 2][r] = v.z; Xs[d0 + 3][r] = v.w;
        float4 w = ysrc[idx];
        Ys[d0 + 0][r] = w.x; Ys[d0 + 1][r] = w.y;
        Ys[d0 + 2][r] = w.z; Ys[d0 + 3][r] = w.w;
    }
    __syncthreads();

    if (t < 64) {
        float s = 0.f;
#pragma unroll
        for (int k = 0; k < DIMN; ++k) { float v = Xs[k][t]; s += v * v; }
        x2s[t] = s;
    } else if (t < 128) {
        int c = t - 64;
        float s = 0.f;
#pragma unroll
        for (int k = 0; k < DIMN; ++k) { float v = Ys[k][c]; s += v * v; }
        y2s[c] = s;
    }
    __syncthreads();

    const int tx = t & 15;
    const int ty = t >> 4;
    float acc[4][4];
#pragma unroll
    for (int r = 0; r < 4; ++r)
#pragma unroll
        for (int c = 0; c < 4; ++c) acc[r][c] = 0.f;

#pragma unroll 4
    for (int k = 0; k < DIMN; ++k) {
        float4 a  = *(const float4*)&Xs[k][ty * 4];
        float4 bv = *(const float4*)&Ys[k][tx * 4];
        float ar[4] = {a.x, a.y, a.z, a.w};
        float bc[4] = {bv.x, bv.y, bv.z, bv.w};
#pragma unroll
        for (int r = 0; r < 4; ++r)
#pragma unroll
            for (int c = 0; c < 4; ++c) acc[r][c] += ar[r] * bc[c];
    }

    float yy0 = y2s[tx * 4 + 0], yy1 = y2s[tx * 4 + 1];
    float yy2 = y2s[tx * 4 + 2], yy3 = y2s[tx * 4 + 3];
    const int jb = j0 + tx * 4;
#pragma unroll
    for (int r = 0; r < 4; ++r) {
        const int ii = i0 + ty * 4 + r;
        float xx = x2s[ty * 4 + r];
        float4 o;
        o.x = (xx + yy0 - 2.f * acc[r][0]) * INV_LN2;
        o.y = (xx + yy1 - 2.f * acc[r][1]) * INV_LN2;
        o.z = (xx + yy2 - 2.f * acc[r][2]) * INV_LN2;
        o.w = (xx + yy3 - 2.f * acc[r][3]) * INV_LN2;
        size_t off = ((size_t)b << 18)
                   + (size_t)(((ii >> 3) << 6) + (jb >> 3)) * 64
                   + ((ii & 7) << 3) + (jb & 7);
        *(float4*)(D + off) = o;
    }
}

// ---------------------------------------------------------------------------
// Kernel 2: soft-DTW, single-wave tile wavefront. One wave (64 lanes) per
// batch; lane p owns rows [8p, 8p+8). Super-step s: lane p computes 8x8 tile
// (p, q=s-p). Inter-lane handoff (bottom row + corner of lane p-1's previous
// tile) via __shfl_up — NO barriers, NO LDS. 127 super-steps.
// Works in base-2 domain: softmin'(a,b,c) = m - log2(1 + 2^(m-mid) + 2^(m-max)).
// D tile for step q+1 is double-buffer prefetched during step q.
// ---------------------------------------------------------------------------
__global__ __launch_bounds__(64) void sdtw_kernel(const float* __restrict__ D,
                                                  float* __restrict__ out) {
    const int p = threadIdx.x;           // lane = row-strip index
    const int b = blockIdx.x;
    const float* tbase = D + ((size_t)b << 18) + (size_t)p * 4096; // tiles (p, *)

    float4 dcur[16], dnext[16];
#pragma unroll
    for (int k = 0; k < 16; ++k) dcur[k] = ((const float4*)tbase)[k];  // tile (p,0)

    float ub[8], rcol[8], brow[8];
#pragma unroll
    for (int c = 0; c < 8; ++c) { ub[c] = BIGF; rcol[c] = BIGF; brow[c] = BIGF; }
    float cor_saved = BIGF;

    for (int s = 0; s < 127; ++s) {
        const int q = s - p;

        // prefetch tile (p, q+1) (clamped; inactive lanes harmlessly reload)
        int qn = q + 1; qn = (qn < 0) ? 0 : (qn > 63 ? 63 : qn);
        const float4* nsrc = (const float4*)(tbase + (size_t)qn * 64);
#pragma unroll
        for (int k = 0; k < 16; ++k) dnext[k] = nsrc[k];

        const bool active = (q >= 0) && (q < 64);
        if (active) {
            const float cor = (q == 0) ? ((p == 0) ? 0.f : BIGF) : cor_saved;
            float lc[8];
#pragma unroll
            for (int r = 0; r < 8; ++r) lc[r] = (q == 0) ? BIGF : rcol[r];

            float prow[8], cur[8];
#pragma unroll
            for (int r = 0; r < 8; ++r) {
#pragma unroll
                for (int c = 0; c < 8; ++c) {
                    float vd, vu, vl;
                    if (r == 0) { vu = ub[c];   vd = (c == 0) ? cor      : ub[c - 1]; }
                    else        { vu = prow[c]; vd = (c == 0) ? lc[r - 1] : prow[c - 1]; }
                    vl = (c == 0) ? lc[r] : cur[c - 1];

                    float m  = fminf(fminf(vd, vu), vl);
                    float md = __builtin_amdgcn_fmed3f(vd, vu, vl);
                    float mx = fmaxf(fmaxf(vd, vu), vl);
                    float ssum = 1.0f + __builtin_amdgcn_exp2f(m - md)
                                      + __builtin_amdgcn_exp2f(m - mx);
                    float4 tq = dcur[(r << 1) + (c >> 2)];
                    int cc = c & 3;
                    float dval = (cc == 0) ? tq.x : (cc == 1) ? tq.y
                               : (cc == 2) ? tq.z : tq.w;
                    cur[c] = dval + m - __builtin_amdgcn_logf(ssum);
                }
#pragma unroll
                for (int c = 0; c < 8; ++c) prow[c] = cur[c];
                rcol[r] = cur[7];
            }
#pragma unroll
            for (int c = 0; c < 8; ++c) brow[c] = cur[c];
        }

        // uniform handoff: corner, then up-boundary from lane p-1's brow
        cor_saved = ub[7];
#pragma unroll
        for (int c = 0; c < 8; ++c) {
            float v = __shfl_up(brow[c], 1, 64);
            ub[c] = (p == 0) ? BIGF : v;
        }
#pragma unroll
        for (int k = 0; k < 16; ++k) dcur[k] = dnext[k];
    }

    if (p == 63) out[b] = brow[7] * LN2F;   // R[511][511] back to natural log domain
}

extern "C" void kernel_launch(void* const* d_in, const int* in_sizes, int n_in,
                              void* d_out, int out_size, void* d_ws, size_t ws_size,
                              hipStream_t stream) {
    const float* X = (const float*)d_in[0];
    const float* Y = (const float*)d_in[1];
    float* Dws = (float*)d_ws;
    float* out = (float*)d_out;

    const size_t per_batch = (size_t)LXN * LYN * sizeof(float);  // 1 MiB
    int chunk = (int)(ws_size / per_batch);
    if (chunk > BATCH) chunk = BATCH;
    if (chunk < 1) chunk = 1;

    for (int b0 = 0; b0 < BATCH; b0 += chunk) {
        int nb = BATCH - b0 < chunk ? BATCH - b0 : chunk;
        dist_kernel<<<dim3(LYN / 64, LXN / 64, nb), 256, 0, stream>>>(
            X + (size_t)b0 * LXN * DIMN, Y + (size_t)b0 * LYN * DIMN, Dws);
        sdtw_kernel<<<nb, 64, 0, stream>>>(Dws, out + b0);
    }
}